// Round 15
// baseline (127.081 us; speedup 1.0000x reference)
//
#include <hip/hip_runtime.h>
#include <stdint.h>

// ColBERT MaxSim on MI355X (gfx950), round 21.
// scores[b,c] = sum_n max_s dot(qs[b,n,:], ps[c,s,:])
// qs: (64, 32, 128) f32, ps: (64, 1024, 128) f32, out: (64, 64) f32.
//
// R20 post-mortem: COMPILE FAIL -- "+v" on a uint4 is a tied INDIRECT
// (4-reg tuple) asm operand, unsupported by AMDGPU lowering. Theory
// untested. R21 = R20 with the pin applied per 32-bit COMPONENT
// ("+v"(qf[bb][k].x) etc.), the supported scalar-VGPR tie. 64 pins, zero
// instructions emitted, same remat-severing semantics.
//
// Recap of the theory: all three single-dispatch attempts (R12/R16/R18)
// died because LLVM rematerializes qf from memory when loop complexity
// rises (loads are visible => "free" to re-issue). Opaque asm severs the
// def chain => remat impossible; alternatives are keep-in-reg (live ~122
// <= 128 budget, fits) or scratch spill (visible in WRITE_SIZE). Body =
// R18 verbatim: single dispatch, f32 gload_lds staging (zero staging
// VGPRs), cvt-at-consume (2x ds_read_b128 + 4 cvt_pk per frag), triple
// buffer, depth-2 counted vmcnt(4), raw s_barrier.
// Pass signal: VGPR >= 96 (R18: 72), FETCH ~33-35 MB, WRITE ~16 B.
// Predict maxsim ~38-48 (visible in top-5), dur 110 -> 95-103.
// Fail (VGPR ~72 / dur > 115): revert R17, declare plateau.

typedef __bf16 bf16x8 __attribute__((ext_vector_type(8)));
typedef float floatx16 __attribute__((ext_vector_type(16)));

union FU { bf16x8 v; uint4 u; };

__device__ inline bf16x8 cvt8(const float4& a, const float4& b) {
  bf16x8 r;
  r[0] = (__bf16)a.x; r[1] = (__bf16)a.y; r[2] = (__bf16)a.z; r[3] = (__bf16)a.w;
  r[4] = (__bf16)b.x; r[5] = (__bf16)b.y; r[6] = (__bf16)b.z; r[7] = (__bf16)b.w;
  return r;
}

__device__ inline float rmax16(const floatx16& a) {
  // Nested fmaxf triples fuse to v_max3_f32.
  float m0 = fmaxf(fmaxf(a[0], a[1]), fmaxf(a[2], a[3]));
  float m1 = fmaxf(fmaxf(a[4], a[5]), fmaxf(a[6], a[7]));
  float m2 = fmaxf(fmaxf(a[8], a[9]), fmaxf(a[10], a[11]));
  float m3 = fmaxf(fmaxf(a[12], a[13]), fmaxf(a[14], a[15]));
  return fmaxf(fmaxf(m0, m1), fmaxf(m2, m3));
}

// global_load_lds: builtin takes AS1/AS3 pointers; C-style casts addrspacecast.
typedef __attribute__((address_space(1))) const void gas_t;
typedef __attribute__((address_space(3))) void las_t;
__device__ inline void gload_lds16f(const float* g, float* l) {
  __builtin_amdgcn_global_load_lds((gas_t*)g, (las_t*)l, 16, 0, 0);
}

#define ZERO16 {0, 0, 0, 0, 0, 0, 0, 0, 0, 0, 0, 0, 0, 0, 0, 0}

__global__ __launch_bounds__(256) void maxsim_kernel(const float* __restrict__ qs,
                                                     const float* __restrict__ ps,
                                                     float* __restrict__ out) {
  const int lane = threadIdx.x & 63;
  const int wave = threadIdx.x >> 6;

  // XCD swizzle: the 8 blocks of doc c all land on XCD c>>3 -> P_c (512 KB
  // f32) L2-resident after the first reader (per-XCD set: 8 docs = 4 MB).
  const int xcd = blockIdx.x & 7;
  const int slot = blockIdx.x >> 3;   // 0..63
  const int c = xcd * 8 + (slot >> 3);
  const int bg = slot & 7;
  const int qb0 = bg * 8 + wave * 2;  // this wave's first query (of 2)

  const int row = lane & 31;          // A-frag: s-row; B-frag: query token n
  const int hi8 = (lane >> 5) * 8;    // K-half selector (elements)

  // Q B-frags f32 -> cvt -> reg in the PROLOGUE, then PINNED via opaque
  // per-component asm: def chains severed => rematerialization impossible.
  // qf[bb][k] = Q[qb0+bb][n=row][k*16 + hi8 + 0..7] as bf16 (64 VGPRs).
  uint4 qf[2][8];
#pragma unroll
  for (int bb = 0; bb < 2; ++bb) {
    const float* q = qs + ((qb0 + bb) * 32 + row) * 128 + hi8;
#pragma unroll
    for (int k = 0; k < 8; ++k) {
      float4 a = *(const float4*)(q + k * 16);
      float4 b = *(const float4*)(q + k * 16 + 4);
      FU f; f.v = cvt8(a, b);
      qf[bb][k] = f.u;
    }
  }
#pragma unroll
  for (int bb = 0; bb < 2; ++bb)
#pragma unroll
    for (int k = 0; k < 8; ++k)
      asm volatile("" : "+v"(qf[bb][k].x), "+v"(qf[bb][k].y),
                        "+v"(qf[bb][k].z), "+v"(qf[bb][k].w));

  // P tile TRIPLE buffer, f32, 32 tokens/tile = 16 KiB each.
  // Chunk m = j*2+h (j = k-group of 16 dims, h = 4-dim half): lane l's 16 B
  // at lds[m*256 + l*4] = P[c][t*32 + (l&31)][j*16 + (l>>5)*8 + h*4 .. +4].
  __shared__ __align__(16) float lds_p[3][4096];

  // Per-lane global element offset (tile tt adds tt*4096 elements).
  const int pg_lane = (c * 1024 + row) * 128 + hi8;

  // Wave w issues global chunks m = 4w..4w+3.
#define STAGE(L, tt)                                                          \
  _Pragma("unroll") for (int jj = 0; jj < 4; ++jj) {                          \
    const int m = wave * 4 + jj;                                              \
    const int j = m >> 1, h = m & 1;                                          \
    gload_lds16f(ps + pg_lane + (tt) * 4096 + j * 16 + h * 4,                 \
                 (L) + m * 256);                                              \
  }

  float* pA = &lds_p[0][0];  // current compute tile
  float* pB = &lds_p[1][0];  // tile t+1 (in flight / landed)
  float* pC = &lds_p[2][0];  // tile t+2 (staging target)

  // Prologue: stage tiles 0 and 1 (8 loads outstanding), wait for tile 0
  // only (vmcnt(4): tile-1's 4 loads stay in flight), collective barrier.
  STAGE(pA, 0)
  STAGE(pB, 1)
  asm volatile("s_waitcnt vmcnt(4)" ::: "memory");
  __builtin_amdgcn_s_barrier();

  float vmax0 = -3.4e38f, vmax1 = -3.4e38f;

#pragma unroll 1
  for (int t = 0; t < 32; ++t) {
    // Issue stage(t+2) into pC BEFORE compute (~2 compute phases to land).
    // pC's last readers were iter t-1, protected by that iter's barrier.
    if (t + 2 < 32) {
      STAGE(pC, t + 2)
    }
    // Compute tile t from pA: per frag 2x ds_read_b128 (f32 lo/hi) ->
    // 4 cvt_pk -> 2 MFMA (q0,q1). Transients immediate-consume.
    const float* lp = pA + lane * 4;
    floatx16 acc0 = ZERO16, acc1 = ZERO16;
#pragma unroll
    for (int k = 0; k < 8; ++k) {
      float4 lo = *(const float4*)(lp + (2 * k) * 256);
      float4 hi = *(const float4*)(lp + (2 * k + 1) * 256);
      bf16x8 af = cvt8(lo, hi);
      FU f0; f0.u = qf[0][k];
      FU f1; f1.u = qf[1][k];
      acc0 = __builtin_amdgcn_mfma_f32_32x32x16_bf16(af, f0.v, acc0, 0, 0, 0);
      acc1 = __builtin_amdgcn_mfma_f32_32x32x16_bf16(af, f1.v, acc1, 0, 0, 0);
    }
    vmax0 = fmaxf(vmax0, rmax16(acc0));
    vmax1 = fmaxf(vmax1, rmax16(acc1));
    // Counted wait: own stage(t+1) landed; in-order retirement leaves only
    // stage(t+2)'s 4 loads in flight ACROSS the barrier. Tail: t=30 drains.
    if (t + 2 < 32) {
      asm volatile("s_waitcnt vmcnt(4)" ::: "memory");
    } else if (t + 1 < 32) {
      asm volatile("s_waitcnt vmcnt(0)" ::: "memory");
    }
    if (t + 1 < 32) __builtin_amdgcn_s_barrier();
    // Rotate: pA <- pB (next compute), pB <- pC, pC <- old pA.
    float* tmp = pA; pA = pB; pB = pC; pC = tmp;
  }

  // acc D-layout: col = lane&31 = token n; lanes l, l^32 hold complementary
  // row-halves -> max-merge, then butterfly-sum the 32 tokens.
  vmax0 = fmaxf(vmax0, __shfl_xor(vmax0, 32, 64));
  vmax1 = fmaxf(vmax1, __shfl_xor(vmax1, 32, 64));
#pragma unroll
  for (int o = 16; o > 0; o >>= 1) {
    vmax0 += __shfl_xor(vmax0, o, 64);
    vmax1 += __shfl_xor(vmax1, o, 64);
  }
  if (lane == 0) {
    out[(qb0 + 0) * 64 + c] = vmax0;
    out[(qb0 + 1) * 64 + c] = vmax1;
  }
}

extern "C" void kernel_launch(void* const* d_in, const int* in_sizes, int n_in,
                              void* d_out, int out_size, void* d_ws, size_t ws_size,
                              hipStream_t stream) {
  const float* qs = (const float*)d_in[0];
  const float* ps = (const float*)d_in[1];
  float* out = (float*)d_out;
  (void)d_ws; (void)ws_size;  // ws poison fill is unconditional; ws gives us nothing

  maxsim_kernel<<<dim3(512), dim3(256), 0, stream>>>(qs, ps, out);
}

// Round 16
// 115.104 us; speedup vs baseline: 1.1040x; 1.1040x over previous
//
#include <hip/hip_runtime.h>
#include <stdint.h>

// ColBERT MaxSim on MI355X (gfx950), round 22.
// scores[b,c] = sum_n max_s dot(qs[b,n,:], ps[c,s,:])
// qs: (64, 32, 128) f32, ps: (64, 1024, 128) f32, out: (64, 64) f32.
//
// R21 post-mortem (diagnostic win): pins compile, no scratch, yet perf
// identical to R18 -- and FETCH 20.5 MB = exactly 2x R11's 10.3 (f32 vs
// bf16 ps), NOT qf re-reads. So R18/R21's cost was the in-loop cvt dep
// chain (ds_read f32 -> lgkm -> 4 cvt_pk -> MFMA, 2x LDS bytes), not
// register demotion. In-loop cvt dead on merits; bf16 precvt restored.
//
// Real arithmetic of R13's 38 us (5700 cyc/64-tok iter/CU): MFMA 2048 cyc,
// LDS reads 2048 cyc (each ds_read feeds only 2 MFMAs), staging 256,
// barriers -- sum-if-serialized = 5700 = observed. Both pipes equally
// loaded; that's why every schedule tweak was neutral.
//
// R22: halve the LDS-read load. Wave w owns queries (w>>1)*4..+3 x subtile
// (w&1): per tile per wave 8 ds_read -> 32 MFMA (1:4 reuse, was 1:2).
// qf[4][8] = 128 VGPRs PINNED via per-component asm (R21-proven): remat
// impossible, spill would show in WRITE_SIZE. Live ~208 <= 256 -> still 2
// waves/SIMD. Epilogue: cross-wave-pair max via red[] LDS (R6 pattern) +
// butterfly sum.
// Predict: maxsim 38 -> 24-30 (invisible), dur 110 -> 95-102, FETCH ~10.3
// MB, WRITE ~16 B. Fail: dur>115 or WRITE>>16B (spill) -> revert R17;
// ~110 neutral -> plateau declared.

typedef __bf16 bf16x8 __attribute__((ext_vector_type(8)));
typedef float floatx16 __attribute__((ext_vector_type(16)));

#define QS_N (64u * 32u * 128u)    // 262144
#define PS_N (64u * 1024u * 128u)  // 8388608

// Static bf16 staging buffer: qs in [0, QS_N), ps in [QS_N, QS_N+PS_N).
__device__ ushort g_bf[QS_N + PS_N];

union FU { bf16x8 v; uint4 u; };

__global__ __launch_bounds__(256) void cvt_kernel(const float* __restrict__ qs,
                                                  const float* __restrict__ ps) {
  const int nq4 = QS_N / 4;
  const int n4 = (QS_N + PS_N) / 4;
  int i = blockIdx.x * 256 + threadIdx.x;
  if (i >= n4) return;
  float4 f = (i < nq4) ? ((const float4*)qs)[i] : ((const float4*)ps)[i - nq4];
  union { ushort4 s; struct { __bf16 a, b, c, d; } h; } o;
  o.h.a = (__bf16)f.x; o.h.b = (__bf16)f.y; o.h.c = (__bf16)f.z; o.h.d = (__bf16)f.w;
  ((ushort4*)g_bf)[i] = o.s;
}

__device__ inline float rmax16(const floatx16& a) {
  // Nested fmaxf triples fuse to v_max3_f32.
  float m0 = fmaxf(fmaxf(a[0], a[1]), fmaxf(a[2], a[3]));
  float m1 = fmaxf(fmaxf(a[4], a[5]), fmaxf(a[6], a[7]));
  float m2 = fmaxf(fmaxf(a[8], a[9]), fmaxf(a[10], a[11]));
  float m3 = fmaxf(fmaxf(a[12], a[13]), fmaxf(a[14], a[15]));
  return fmaxf(fmaxf(m0, m1), fmaxf(m2, m3));
}

// global_load_lds: builtin takes AS1/AS3 pointers; C-style casts addrspacecast.
typedef __attribute__((address_space(1))) const void gas_t;
typedef __attribute__((address_space(3))) void las_t;
__device__ inline void gload_lds16(const ushort* g, ushort* l) {
  __builtin_amdgcn_global_load_lds((gas_t*)g, (las_t*)l, 16, 0, 0);
}

#define ZERO16 {0, 0, 0, 0, 0, 0, 0, 0, 0, 0, 0, 0, 0, 0, 0, 0}

__global__ __launch_bounds__(256) void maxsim_kernel(float* __restrict__ out) {
  const ushort* qsb = g_bf;
  const ushort* psb = g_bf + QS_N;

  const int lane = threadIdx.x & 63;
  const int wave = threadIdx.x >> 6;

  // XCD swizzle: the 8 blocks of doc c all land on XCD c>>3 -> P_c (256 KB
  // bf16) L2-resident after the first reader (per-XCD set: 8 docs = 2 MB).
  const int xcd = blockIdx.x & 7;
  const int slot = blockIdx.x >> 3;   // 0..63
  const int c = xcd * 8 + (slot >> 3);
  const int bg = slot & 7;

  // Wave -> (query quad, subtile) mapping: 1 ds_read feeds 4 MFMAs.
  const int qgrp = wave >> 1;         // 0: queries bg*8+0..3, 1: +4..7
  const int usel = wave & 1;          // which 32-token subtile of each tile
  const int qb0 = bg * 8 + qgrp * 4;

  const int row = lane & 31;          // A-frag: s-row; B-frag: query token n
  const int hi8 = (lane >> 5) * 8;    // K-half selector (elements)

  // Q B-frags global->reg (L2-hot 16B loads), then PINNED via per-component
  // opaque asm (R21-proven): remat impossible, must stay in registers.
  // qf[bb][k] = Q[qb0+bb][n=row][k*16 + hi8 + 0..7] (128 VGPRs).
  uint4 qf[4][8];
#pragma unroll
  for (int bb = 0; bb < 4; ++bb) {
    const ushort* q = qsb + ((qb0 + bb) * 32 + row) * 128 + hi8;
#pragma unroll
    for (int k = 0; k < 8; ++k)
      qf[bb][k] = *(const uint4*)(q + k * 16);
  }
#pragma unroll
  for (int bb = 0; bb < 4; ++bb)
#pragma unroll
    for (int k = 0; k < 8; ++k)
      asm volatile("" : "+v"(qf[bb][k].x), "+v"(qf[bb][k].y),
                        "+v"(qf[bb][k].z), "+v"(qf[bb][k].w));

  // P tile double-buffer, 64 tokens/tile = 16 KiB each, A-frag order:
  // sub-tile u (32 rows) at u*8192 B, chunk j (=k) at j*1024 B, lane at 16 B.
  __shared__ __align__(16) ushort lds_p[2][8192];

  // Per-lane global element offset (add s-offset*128 + j*16 per chunk).
  const int pg_lane = (c * 1024 + row) * 128 + hi8;

  // Wave w issues global chunks m = 4w..4w+3 (u = m>>3, j = m&7).
#define STAGE(L, tt)                                                          \
  _Pragma("unroll") for (int jj = 0; jj < 4; ++jj) {                          \
    const int m = wave * 4 + jj;                                              \
    const int u = m >> 3, j = m & 7;                                          \
    gload_lds16(psb + pg_lane + (tt) * 8192 + u * 32 * 128 + j * 16,          \
                (L) + u * 4096 + j * 512);                                    \
  }

  // Prologue: stage tile 0.
  STAGE(&lds_p[0][0], 0)
  __syncthreads();

  float vmax[4];
#pragma unroll
  for (int bb = 0; bb < 4; ++bb) vmax[bb] = -3.4e38f;
  int cb = 0;

#pragma unroll 1
  for (int t = 0; t < 16; ++t) {
    // Stage tile t+1; latency hides under this tile's 32 MFMAs.
    if (t < 15) {
      STAGE(&lds_p[cb ^ 1][0], t + 1)
    }
    // Compute: THIS wave's subtile only, 4 acc chains, 1 ds_read : 4 MFMA.
    const ushort* lp = &lds_p[cb][usel * 4096] + lane * 8;
    floatx16 a0 = ZERO16, a1 = ZERO16, a2 = ZERO16, a3 = ZERO16;
#pragma unroll
    for (int k = 0; k < 8; ++k) {
      bf16x8 af = *(const bf16x8*)(lp + k * 512);
      FU f0; f0.u = qf[0][k];
      FU f1; f1.u = qf[1][k];
      FU f2; f2.u = qf[2][k];
      FU f3; f3.u = qf[3][k];
      a0 = __builtin_amdgcn_mfma_f32_32x32x16_bf16(af, f0.v, a0, 0, 0, 0);
      a1 = __builtin_amdgcn_mfma_f32_32x32x16_bf16(af, f1.v, a1, 0, 0, 0);
      a2 = __builtin_amdgcn_mfma_f32_32x32x16_bf16(af, f2.v, a2, 0, 0, 0);
      a3 = __builtin_amdgcn_mfma_f32_32x32x16_bf16(af, f3.v, a3, 0, 0, 0);
    }
    vmax[0] = fmaxf(vmax[0], rmax16(a0));
    vmax[1] = fmaxf(vmax[1], rmax16(a1));
    vmax[2] = fmaxf(vmax[2], rmax16(a2));
    vmax[3] = fmaxf(vmax[3], rmax16(a3));
    // Barrier: staging of t+1 landed AND all readers of cb are done.
    __syncthreads();
    cb ^= 1;
  }

  // Per-token max: lanes l, l^32 hold complementary row-halves of token
  // n = lane&31.
#pragma unroll
  for (int bb = 0; bb < 4; ++bb)
    vmax[bb] = fmaxf(vmax[bb], __shfl_xor(vmax[bb], 32, 64));

  // Cross-wave merge: waves 2g and 2g+1 hold the two subtile-halves of
  // query quad g. red[wave][bb][n] -> max-merge -> butterfly-sum over n.
  __shared__ float red[4][4][32];
  if (lane < 32) {
#pragma unroll
    for (int bb = 0; bb < 4; ++bb) red[wave][bb][lane] = vmax[bb];
  }
  __syncthreads();
  {
    const int q = threadIdx.x >> 5;   // 0..7 (query within block)
    const int n = threadIdx.x & 31;   // query token
    float m = fmaxf(red[(q >> 2) * 2][q & 3][n], red[(q >> 2) * 2 + 1][q & 3][n]);
#pragma unroll
    for (int o = 16; o > 0; o >>= 1) m += __shfl_xor(m, o, 32);
    if (n == 0) out[(bg * 8 + q) * 64 + c] = m;
  }
}

extern "C" void kernel_launch(void* const* d_in, const int* in_sizes, int n_in,
                              void* d_out, int out_size, void* d_ws, size_t ws_size,
                              hipStream_t stream) {
  const float* qs = (const float*)d_in[0];
  const float* ps = (const float*)d_in[1];
  float* out = (float*)d_out;
  (void)d_ws; (void)ws_size;  // ws poison fill is unconditional; ws gives us nothing

  const int n4 = (int)((QS_N + PS_N) / 4);
  cvt_kernel<<<(n4 + 255) / 256, 256, 0, stream>>>(qs, ps);
  maxsim_kernel<<<dim3(512), dim3(256), 0, stream>>>(out);
}

// Round 17
// 111.270 us; speedup vs baseline: 1.1421x; 1.0345x over previous
//
#include <hip/hip_runtime.h>
#include <stdint.h>

// ColBERT MaxSim on MI355X (gfx950), round 23.
// scores[b,c] = sum_n max_s dot(qs[b,n,:], ps[c,s,:])
// qs: (64, 32, 128) f32, ps: (64, 1024, 128) f32, out: (64, 64) f32.
//
// R22 post-mortem: 1:4 LDS reuse made maxsim slightly WORSE (43 vs 38) with
// pins proven working (no spill, no demotion) -> the serialized LDS+MFMA
// model is dead; all compute-structure variants land 38-43 us (latency/
// barrier convoy at 2 waves/SIMD). Within-kernel levers exhausted.
//
// R23: spend the proven pin on the experiment whose ACCOUNTING was always
// positive: R12's single-dispatch reg-transit staging (global f32 ->
// v_cvt_pk_bf16_f32 -> ds_write_b128), which deletes the cvt dispatch
// (8 us) + one inter-dispatch gap (~7 us). R12's only failure was qf
// demotion (VGPR 92) -- now impossible (per-component asm pins, R21).
// Core = R13's best-performing compute mapping (2 queries/wave, 64-token
// tiles, 2 acc chains, one barrier/iter); staging = T14 order: issue 8
// f32x4 loads for t+1 -> compute t (32 MFMA, ~2000 cyc covers L2 latency)
// -> cvt+write to back buffer -> barrier. Regs ~148 <= 170, grid-limited
// occupancy unaffected.
// Predict: ONE dispatch, dur 110.2 -> 96-101; maxsim ~39-44 visible, VGPR
// 144-168, WRITE ~16 B, FETCH 20-33 MB, conflicts 0. Fail (maxsim>50 or
// VGPR<96): revert R17, declare plateau.

typedef __bf16 bf16x8 __attribute__((ext_vector_type(8)));
typedef float floatx16 __attribute__((ext_vector_type(16)));

union FU { bf16x8 v; uint4 u; };

__device__ inline bf16x8 cvt8(const float4& a, const float4& b) {
  bf16x8 r;
  r[0] = (__bf16)a.x; r[1] = (__bf16)a.y; r[2] = (__bf16)a.z; r[3] = (__bf16)a.w;
  r[4] = (__bf16)b.x; r[5] = (__bf16)b.y; r[6] = (__bf16)b.z; r[7] = (__bf16)b.w;
  return r;
}

__device__ inline float rmax16(const floatx16& a) {
  // Nested fmaxf triples fuse to v_max3_f32.
  float m0 = fmaxf(fmaxf(a[0], a[1]), fmaxf(a[2], a[3]));
  float m1 = fmaxf(fmaxf(a[4], a[5]), fmaxf(a[6], a[7]));
  float m2 = fmaxf(fmaxf(a[8], a[9]), fmaxf(a[10], a[11]));
  float m3 = fmaxf(fmaxf(a[12], a[13]), fmaxf(a[14], a[15]));
  return fmaxf(fmaxf(m0, m1), fmaxf(m2, m3));
}

#define ZERO16 {0, 0, 0, 0, 0, 0, 0, 0, 0, 0, 0, 0, 0, 0, 0, 0}

__global__ __launch_bounds__(256) void maxsim_kernel(const float* __restrict__ qs,
                                                     const float* __restrict__ ps,
                                                     float* __restrict__ out) {
  const int lane = threadIdx.x & 63;
  const int wave = threadIdx.x >> 6;

  // XCD swizzle: the 8 blocks of doc c all land on XCD c>>3 -> P_c (512 KB
  // f32) L2-resident after the first reader (per-XCD set: 8 docs = 4 MB).
  const int xcd = blockIdx.x & 7;
  const int slot = blockIdx.x >> 3;   // 0..63
  const int c = xcd * 8 + (slot >> 3);
  const int bg = slot & 7;
  const int qb0 = bg * 8 + wave * 2;  // this wave's first query (of 2)

  const int row = lane & 31;          // A-frag: s-row; B-frag: query token n
  const int hi8 = (lane >> 5) * 8;    // K-half selector (elements)

  // Q B-frags f32 -> cvt -> reg in the PROLOGUE (R14-proven safe), then
  // PINNED per 32-bit component (R21-proven): remat impossible.
  // qf[bb][k] = Q[qb0+bb][n=row][k*16 + hi8 + 0..7] as bf16 (64 VGPRs).
  uint4 qf[2][8];
#pragma unroll
  for (int bb = 0; bb < 2; ++bb) {
    const float* q = qs + ((qb0 + bb) * 32 + row) * 128 + hi8;
#pragma unroll
    for (int k = 0; k < 8; ++k) {
      float4 a = *(const float4*)(q + k * 16);
      float4 b = *(const float4*)(q + k * 16 + 4);
      FU f; f.v = cvt8(a, b);
      qf[bb][k] = f.u;
    }
  }
#pragma unroll
  for (int bb = 0; bb < 2; ++bb)
#pragma unroll
    for (int k = 0; k < 8; ++k)
      asm volatile("" : "+v"(qf[bb][k].x), "+v"(qf[bb][k].y),
                        "+v"(qf[bb][k].z), "+v"(qf[bb][k].w));

  // P tile double-buffer, bf16, 64 tokens/tile = 16 KiB each, A-frag order:
  // sub-tile u (32 rows) at u*8192 B, chunk j (=k) at j*1024 B, lane at 16 B.
  __shared__ __align__(16) ushort lds_p[2][8192];

  // Per-lane f32 global element offset (tile tt adds tt*64*128).
  const float* pg = ps + (c * 1024 + row) * 128 + hi8;

  // Wave w stages chunks m = 4w..4w+3 (u = m>>3, j = m&7): per chunk, 2
  // float4 loads; lane l covers row u*32+(l&31), dims j*16+(l>>5)*8+0..7.
  float4 F[8];

#define STAGE_LOAD(tt)                                                        \
  _Pragma("unroll") for (int jj = 0; jj < 4; ++jj) {                          \
    const int m = wave * 4 + jj;                                              \
    const int u = m >> 3, j = m & 7;                                          \
    const float* src = pg + (tt) * 8192 + u * 32 * 128 + j * 16;              \
    F[2 * jj] = *(const float4*)src;                                          \
    F[2 * jj + 1] = *(const float4*)(src + 4);                                \
  }

#define STAGE_WRITE(B)                                                        \
  _Pragma("unroll") for (int jj = 0; jj < 4; ++jj) {                          \
    const int m = wave * 4 + jj;                                              \
    const int u = m >> 3, j = m & 7;                                          \
    *(bf16x8*)(&(B)[u * 4096 + j * 512 + lane * 8]) =                         \
        cvt8(F[2 * jj], F[2 * jj + 1]);                                       \
  }

  // Prologue: stage tile 0.
  STAGE_LOAD(0)
  STAGE_WRITE(lds_p[0])
  __syncthreads();

  float vmax0 = -3.4e38f, vmax1 = -3.4e38f;
  int cb = 0;

#pragma unroll 1
  for (int t = 0; t < 16; ++t) {
    // T14: issue next tile's f32 loads NOW; ~2000 cyc of MFMA covers L2.
    if (t < 15) {
      STAGE_LOAD(t + 1)
    }
    // Compute tile t (R13's best mapping: 2 subtiles x 2 queries, 2 chains).
    const ushort* lp = &lds_p[cb][0] + lane * 8;
#pragma unroll
    for (int u = 0; u < 2; ++u) {
      floatx16 acc0 = ZERO16, acc1 = ZERO16;
#pragma unroll
      for (int k = 0; k < 8; ++k) {
        bf16x8 af = *(const bf16x8*)(lp + u * 4096 + k * 512);
        FU f0; f0.u = qf[0][k];
        FU f1; f1.u = qf[1][k];
        acc0 = __builtin_amdgcn_mfma_f32_32x32x16_bf16(af, f0.v, acc0, 0, 0, 0);
        acc1 = __builtin_amdgcn_mfma_f32_32x32x16_bf16(af, f1.v, acc1, 0, 0, 0);
      }
      vmax0 = fmaxf(vmax0, rmax16(acc0));
      vmax1 = fmaxf(vmax1, rmax16(acc1));
    }
    // Write staged tile t+1 into the back buffer (loads have landed by now;
    // compiler inserts the vmcnt wait at first use of F), then barrier.
    if (t < 15) {
      STAGE_WRITE(lds_p[cb ^ 1])
    }
    __syncthreads();
    cb ^= 1;
  }

  // acc D-layout: col = lane&31 = token n; lanes l, l^32 hold complementary
  // row-halves -> max-merge, then butterfly-sum the 32 tokens.
  vmax0 = fmaxf(vmax0, __shfl_xor(vmax0, 32, 64));
  vmax1 = fmaxf(vmax1, __shfl_xor(vmax1, 32, 64));
#pragma unroll
  for (int o = 16; o > 0; o >>= 1) {
    vmax0 += __shfl_xor(vmax0, o, 64);
    vmax1 += __shfl_xor(vmax1, o, 64);
  }
  if (lane == 0) {
    out[(qb0 + 0) * 64 + c] = vmax0;
    out[(qb0 + 1) * 64 + c] = vmax1;
  }
}

extern "C" void kernel_launch(void* const* d_in, const int* in_sizes, int n_in,
                              void* d_out, int out_size, void* d_ws, size_t ws_size,
                              hipStream_t stream) {
  const float* qs = (const float*)d_in[0];
  const float* ps = (const float*)d_in[1];
  float* out = (float*)d_out;
  (void)d_ws; (void)ws_size;  // ws poison fill is unconditional; ws gives us nothing

  maxsim_kernel<<<dim3(512), dim3(256), 0, stream>>>(qs, ps, out);
}